// Round 5
// baseline (787.183 us; speedup 1.0000x reference)
//
#include <hip/hip_runtime.h>
#include <hip/hip_bf16.h>

// DEChannelPool: 6 soft-morphology branches + per-channel BN + 1x1 conv + BN + ReLU.
// Inputs fp32, output fp32.
// exp(beta*(w±x)) = exp(beta*w)*exp(±beta*x); BN+conv fold to alpha*log(S)+const,
// const cancels in final scalar BN.
// R5: precomputed PADDED bf16x2 exp-field in ws (removes exp/bounds/div from hot
// loops); 32x32 tile, 4 px/thread (VGPR<=64 -> 8 waves/SIMD); j-column fragments;
// double-buffered LDS in pass 2 (1 barrier/channel).

#define BETA 15.0f
#define MSHIFT 25.0f
#define INV_BETA (1.0f/15.0f)
#define EPSB 1e-5f
#define Hn 192
#define Wn 192
#define HWn (192*192)
#define N1 (8*192*192)
#define SFLOOR 1e-37f

#define PSTR 200            // padded row stride (u32 elems)
#define PLANE 40000         // padded plane stride (u32 elems), 200x200
#define TILE 32
#define TD 38               // staged tile dim (32+2*3)
#define TLS 40              // LDS row stride (u32)
#define NTW 6
#define NTILES 36

// workspace layout (4-byte units)
#define WS_SUM   0
#define WS_SQS   384
#define WS_SCAL  768
#define WS_ALPHA 772
#define WS_WG    1156
#define WS_YE    4612
#define WS_YD    (4612 + 294912)
#define WS_ZERO_END (4612 + 2*294912)    // 594436 -> memset region
#define WS_EF    594944                  // aligned exp-field start
// total ws use = (594944 + 512*40000)*4 B  ~= 84.3 MB

__device__ __forceinline__ float bflo(unsigned u) { return __uint_as_float(u << 16); }
__device__ __forceinline__ float bfhi(unsigned u) { return __uint_as_float(u & 0xffff0000u); }

__global__ void k_wexp(const float* __restrict__ we,
                       const float* __restrict__ wd,
                       float* __restrict__ wg) {
    int idx = blockIdx.x * 256 + threadIdx.x;
    if (idx >= 3456) return;
    int kb = idx / 576;
    int rem = idx - kb * 576;
    float w = (kb < 3) ? we[kb * 576 + rem] : wd[(kb - 3) * 576 + rem];
    wg[idx] = __expf(BETA * w);
}

__global__ __launch_bounds__(256) void k_exp(const float* __restrict__ x,
                                             unsigned* __restrict__ ef) {
    int idx = blockIdx.x * 256 + threadIdx.x;
    if (idx >= PLANE) return;
    int p = blockIdx.y;
    int r = idx / PSTR, c = idx - r * PSTR;
    int gh = r - 3, gw = c - 3;
    bool ok = ((unsigned)gh < (unsigned)Hn) && ((unsigned)gw < (unsigned)Wn);
    float bx = 0.f;
    if (ok) bx = BETA * x[(size_t)p * HWn + gh * Wn + gw];
    float em = __expf(-bx - MSHIFT);
    float ep = __expf(bx - MSHIFT);
    union { __hip_bfloat16 h; unsigned short s; } a, b;
    a.h = __float2bfloat16(em);
    b.h = __float2bfloat16(ep);
    ef[(size_t)p * PLANE + idx] = (unsigned)a.s | ((unsigned)b.s << 16);
}

__device__ __forceinline__ void stage_pad(unsigned* E, const unsigned* __restrict__ src,
                                          int tid) {
    const int row = tid >> 5, col = tid & 31;
#pragma unroll
    for (int rr = 0; rr < 5; ++rr) {
        int r = row + rr * 8;
        if (r < TD) {
            const unsigned* s = src + r * PSTR;
            E[r * TLS + col] = s[col];
            if (col < 6) E[r * TLS + 32 + col] = s[32 + col];
        }
    }
}

__global__ __launch_bounds__(256) void k_morph_stats(
    const unsigned* __restrict__ ef, const float* __restrict__ wg,
    float* __restrict__ sum, float* __restrict__ sqs) {
    __shared__ unsigned E[TD * TLS];
    const int tid = threadIdx.x;
    const int p = blockIdx.y;            // b*64 + c
    const int c = p & 63;
    const int t = blockIdx.x;
    const int h0 = (t / NTW) * TILE, w0 = (t % NTW) * TILE;

    stage_pad(E, ef + (size_t)p * PLANE + h0 * PSTR + w0, tid);
    __syncthreads();

    const int px3 = (tid & 31) + 3;
    const int r0 = (tid >> 5) * 4;
    float s[6] = {0,0,0,0,0,0}, q[6] = {0,0,0,0,0,0};
#pragma unroll
    for (int br = 0; br < 3; ++br) {
        const int d = br + 1;
        const int nr = 4 + 2 * d;
        float SEa[4] = {0,0,0,0}, SDa[4] = {0,0,0,0};
#pragma unroll
        for (int j = 0; j < 3; ++j) {
            float WE3[3], WD3[3];
#pragma unroll
            for (int i = 0; i < 3; ++i) {
                WE3[i] = wg[(br * 64 + c) * 9 + i * 3 + j];
                WD3[i] = wg[((br + 3) * 64 + c) * 9 + i * 3 + j];
            }
            float ex[10], ey[10];
#pragma unroll
            for (int r = 0; r < nr; ++r) {
                unsigned u = E[(r0 + 3 - d + r) * TLS + px3 + (j - 1) * d];
                ex[r] = bflo(u); ey[r] = bfhi(u);
            }
#pragma unroll
            for (int k = 0; k < 4; ++k)
#pragma unroll
                for (int i = 0; i < 3; ++i) {
                    SEa[k] = fmaf(WE3[i], ex[k + i * d], SEa[k]);
                    SDa[k] = fmaf(WD3[i], ey[k + i * d], SDa[k]);
                }
        }
#pragma unroll
        for (int k = 0; k < 4; ++k) {
            float me = -(__logf(fmaxf(SEa[k], SFLOOR)) + MSHIFT) * INV_BETA;
            float md =  (__logf(fmaxf(SDa[k], SFLOOR)) + MSHIFT) * INV_BETA;
            s[br]     += me; q[br]     = fmaf(me, me, q[br]);
            s[br + 3] += md; q[br + 3] = fmaf(md, md, q[br + 3]);
        }
    }
    const int lane = tid & 63;
#pragma unroll
    for (int v = 0; v < 6; ++v) {
        float a = s[v], b2 = q[v];
#pragma unroll
        for (int off = 32; off; off >>= 1) {
            a  += __shfl_down(a, off, 64);
            b2 += __shfl_down(b2, off, 64);
        }
        if (lane == 0) {
            atomicAdd(&sum[v * 64 + c], a);
            atomicAdd(&sqs[v * 64 + c], b2);
        }
    }
}

__global__ void k_alpha(const float* __restrict__ sum, const float* __restrict__ sqs,
                        const float* __restrict__ bn_ge,
                        const float* __restrict__ bn_gd,
                        const float* __restrict__ conve,
                        const float* __restrict__ convd,
                        float* __restrict__ alpha) {
    int tid = threadIdx.x;
    if (tid >= 384) return;
    float mean = sum[tid] * (1.0f / N1);
    float var  = sqs[tid] * (1.0f / N1) - mean * mean;
    float inv  = rsqrtf(fmaxf(var, 0.f) + EPSB);
    float g, cw, sgn;
    if (tid < 192) { g = bn_ge[tid];       cw = conve[tid];       sgn = -1.f; }
    else           { g = bn_gd[tid - 192]; cw = convd[tid - 192]; sgn =  1.f; }
    alpha[tid] = sgn * cw * g * inv * INV_BETA;
}

__global__ __launch_bounds__(256) void k_reduce_c(
    const unsigned* __restrict__ ef, const float* __restrict__ wg,
    const float* __restrict__ alpha, float* __restrict__ ye, float* __restrict__ yd) {
    __shared__ unsigned EB[2][TD * TLS];
    const int tid = threadIdx.x;
    const int t = blockIdx.x;             // 36 tiles
    const int bz = blockIdx.y;            // b*8 + chunk
    const int b = bz >> 3, chunk = bz & 7;
    const int h0 = (t / NTW) * TILE, w0 = (t % NTW) * TILE;
    const int px3 = (tid & 31) + 3;
    const int r0 = (tid >> 5) * 4;
    const int c0 = chunk * 8;
    float accE[4] = {0,0,0,0}, accD[4] = {0,0,0,0};

    const unsigned* base = ef + (size_t)(b * 64 + c0) * PLANE + h0 * PSTR + w0;
    stage_pad(EB[0], base, tid);
    __syncthreads();

    for (int ci = 0; ci < 8; ++ci) {
        const int c = c0 + ci;
        const unsigned* E = EB[ci & 1];
        if (ci < 7)
            stage_pad(EB[(ci + 1) & 1], base + (size_t)(ci + 1) * PLANE, tid);
#pragma unroll
        for (int br = 0; br < 3; ++br) {
            const int d = br + 1;
            const int nr = 4 + 2 * d;
            const float aE = alpha[br * 64 + c];
            const float aD = alpha[(br + 3) * 64 + c];
            float SEa[4] = {0,0,0,0}, SDa[4] = {0,0,0,0};
#pragma unroll
            for (int j = 0; j < 3; ++j) {
                float WE3[3], WD3[3];
#pragma unroll
                for (int i = 0; i < 3; ++i) {
                    WE3[i] = wg[(br * 64 + c) * 9 + i * 3 + j];
                    WD3[i] = wg[((br + 3) * 64 + c) * 9 + i * 3 + j];
                }
                float ex[10], ey[10];
#pragma unroll
                for (int r = 0; r < nr; ++r) {
                    unsigned u = E[(r0 + 3 - d + r) * TLS + px3 + (j - 1) * d];
                    ex[r] = bflo(u); ey[r] = bfhi(u);
                }
#pragma unroll
                for (int k = 0; k < 4; ++k)
#pragma unroll
                    for (int i = 0; i < 3; ++i) {
                        SEa[k] = fmaf(WE3[i], ex[k + i * d], SEa[k]);
                        SDa[k] = fmaf(WD3[i], ey[k + i * d], SDa[k]);
                    }
            }
#pragma unroll
            for (int k = 0; k < 4; ++k) {
                accE[k] = fmaf(aE, __logf(fmaxf(SEa[k], SFLOOR)), accE[k]);
                accD[k] = fmaf(aD, __logf(fmaxf(SDa[k], SFLOOR)), accD[k]);
            }
        }
        __syncthreads();
    }
#pragma unroll
    for (int k = 0; k < 4; ++k) {
        int idx = b * HWn + (h0 + r0 + k) * Wn + (w0 + px3 - 3);
        atomicAdd(&ye[idx], accE[k]);
        atomicAdd(&yd[idx], accD[k]);
    }
}

__global__ __launch_bounds__(256) void k_fstats(const float* __restrict__ ye,
                                                const float* __restrict__ yd,
                                                float* __restrict__ scal) {
    int i = blockIdx.x * 256 + threadIdx.x;
    float a = ye[i], b = yd[i];
    float v[4] = {a, a * a, b, b * b};
    __shared__ float red[4][4];
    int lane = threadIdx.x & 63, wv = threadIdx.x >> 6;
#pragma unroll
    for (int k = 0; k < 4; ++k) {
        float tv = v[k];
#pragma unroll
        for (int off = 32; off; off >>= 1) tv += __shfl_down(tv, off, 64);
        if (lane == 0) red[wv][k] = tv;
    }
    __syncthreads();
    if (threadIdx.x < 4)
        atomicAdd(&scal[threadIdx.x],
                  red[0][threadIdx.x] + red[1][threadIdx.x] + red[2][threadIdx.x] + red[3][threadIdx.x]);
}

__global__ __launch_bounds__(256) void k_final(
    const float* __restrict__ ye, const float* __restrict__ yd,
    const float* __restrict__ scal,
    const float* __restrict__ g_e, const float* __restrict__ b_e,
    const float* __restrict__ g_d, const float* __restrict__ b_d,
    float* __restrict__ out) {
    int i = blockIdx.x * 256 + threadIdx.x;
    float me_ = scal[0] * (1.0f / N1);
    float ve  = scal[1] * (1.0f / N1) - me_ * me_;
    float ie  = rsqrtf(fmaxf(ve, 0.f) + EPSB);
    float md_ = scal[2] * (1.0f / N1);
    float vd  = scal[3] * (1.0f / N1) - md_ * md_;
    float idv = rsqrtf(fmaxf(vd, 0.f) + EPSB);
    float ge = g_e[0], be = b_e[0];
    float gd = g_d[0], bd = b_d[0];
    int b = i / HWn, rem = i - b * HWn;
    float oe = fmaxf(ge * (ye[i] - me_) * ie + be, 0.f);
    float od = fmaxf(gd * (yd[i] - md_) * idv + bd, 0.f);
    out[(size_t)(b * 2) * HWn + rem]     = oe;
    out[(size_t)(b * 2 + 1) * HWn + rem] = od;
}

extern "C" void kernel_launch(void* const* d_in, const int* in_sizes, int n_in,
                              void* d_out, int out_size, void* d_ws, size_t ws_size,
                              hipStream_t stream) {
    const float* x     = (const float*)d_in[0];
    const float* we    = (const float*)d_in[1];
    const float* wd    = (const float*)d_in[2];
    const float* bn_ge = (const float*)d_in[3];
    const float* bn_gd = (const float*)d_in[5];
    const float* conve = (const float*)d_in[7];
    const float* convd = (const float*)d_in[8];
    const float* g_e   = (const float*)d_in[9];
    const float* b_e   = (const float*)d_in[10];
    const float* g_d   = (const float*)d_in[11];
    const float* b_d   = (const float*)d_in[12];
    float* ws = (float*)d_ws;
    unsigned* ef = (unsigned*)d_ws + WS_EF;

    hipMemsetAsync(d_ws, 0, (size_t)WS_ZERO_END * sizeof(float), stream);
    hipLaunchKernelGGL(k_wexp, dim3(14), dim3(256), 0, stream, we, wd, ws + WS_WG);
    hipLaunchKernelGGL(k_exp, dim3((PLANE + 255) / 256, 512), dim3(256), 0, stream, x, ef);
    hipLaunchKernelGGL(k_morph_stats, dim3(NTILES, 512), dim3(256), 0, stream,
                       ef, ws + WS_WG, ws + WS_SUM, ws + WS_SQS);
    hipLaunchKernelGGL(k_alpha, dim3(1), dim3(384), 0, stream,
                       ws + WS_SUM, ws + WS_SQS, bn_ge, bn_gd, conve, convd, ws + WS_ALPHA);
    hipLaunchKernelGGL(k_reduce_c, dim3(NTILES, 64), dim3(256), 0, stream,
                       ef, ws + WS_WG, ws + WS_ALPHA, ws + WS_YE, ws + WS_YD);
    hipLaunchKernelGGL(k_fstats, dim3(1152), dim3(256), 0, stream,
                       ws + WS_YE, ws + WS_YD, ws + WS_SCAL);
    hipLaunchKernelGGL(k_final, dim3(1152), dim3(256), 0, stream,
                       ws + WS_YE, ws + WS_YD, ws + WS_SCAL, g_e, b_e, g_d, b_d,
                       (float*)d_out);
}

// Round 7
// 441.569 us; speedup vs baseline: 1.7827x; 1.7827x over previous
//
#include <hip/hip_runtime.h>
#include <hip/hip_bf16.h>

// DEChannelPool: 6 soft-morphology branches + per-channel BN + 1x1 conv + BN + ReLU.
// Inputs fp32, output fp32.
// exp(beta*(w±x)) = exp(beta*w)*exp(±beta*x); BN+conv fold to alpha*log(S)+const,
// const cancels in final scalar BN.
// R7 = R6 resubmit (R6 failed with a harness-level Trio exception, no test output):
// ZERO hot atomics (r3/4/5 were serialized at ~1.65 atomics/ns on sum/sqs).
// Pass1 -> per-block partial stores + k_red. Pass2 -> 2 half-channel partial planes,
// plain stores, merged in k_merge. bf16x2 exp field (unpadded), unpacked to float2
// at staging so inner loop uses ds_read_b64 with no unpack.

#define BETA 15.0f
#define MSHIFT 25.0f
#define INV_BETA (1.0f/15.0f)
#define EPSB 1e-5f
#define Hn 192
#define Wn 192
#define HWn (192*192)
#define N1 (8*192*192)
#define SFLOOR 1e-37f

// workspace layout (4-byte units)
#define WS_SUM   0
#define WS_SQS   384
#define WS_SCAL  768
#define WS_ALPHA 772
#define WS_WG    1156
#define WS_PART  4612                       // 768*288 = 221184
#define WS_YE    225796                     // 294912
#define WS_YD    520708                     // 294912
#define WS_PYE   815620                     // 2*294912
#define WS_PYD   1405444                    // 2*294912 -> ends 1995268
#define WS_EF    1995520                    // u32 units; 512*36864 -> total 83.5 MB

__device__ __forceinline__ unsigned packbf(float a, float b) {
    union { __hip_bfloat16 h; unsigned short s; } ua, ub;
    ua.h = __float2bfloat16(a); ub.h = __float2bfloat16(b);
    return (unsigned)ua.s | ((unsigned)ub.s << 16);
}
__device__ __forceinline__ float2 unpackbf(unsigned u) {
    return make_float2(__uint_as_float(u << 16), __uint_as_float(u & 0xffff0000u));
}

__global__ void k_wexp(const float* __restrict__ we,
                       const float* __restrict__ wd,
                       float* __restrict__ wg) {
    int idx = blockIdx.x * 256 + threadIdx.x;
    if (idx >= 3456) return;
    int kb = idx / 576;
    int rem = idx - kb * 576;
    float w = (kb < 3) ? we[kb * 576 + rem] : wd[(kb - 3) * 576 + rem];
    wg[idx] = __expf(BETA * w);
}

__global__ __launch_bounds__(256) void k_exp(const float* __restrict__ x,
                                             unsigned* __restrict__ ef) {
    size_t i = (size_t)blockIdx.x * 256 + threadIdx.x;   // grid exactly covers 512*HWn
    float bx = BETA * x[i];
    ef[i] = packbf(__expf(-bx - MSHIFT), __expf(bx - MSHIFT));
}

// stage NR rows x 38 cols from an unpadded plane into float2 LDS (row stride 39)
template <int NR>
__device__ __forceinline__ void stage_t(float2* E, const unsigned* __restrict__ plane,
                                        int h0, int w0, int tid, unsigned p0) {
    const int row = tid >> 5, col = tid & 31;
#pragma unroll
    for (int rr = 0; rr < (NR + 7) / 8; ++rr) {
        int r = row + rr * 8;
        if (r < NR) {
            int gh = h0 - 3 + r;
            bool rok = ((unsigned)gh < (unsigned)Hn);
            int ghc = min(max(gh, 0), Hn - 1);
            {
                int gw = w0 - 3 + col;
                int gwc = min(max(gw, 0), Wn - 1);
                unsigned u = plane[ghc * Wn + gwc];
                bool ok = rok && ((unsigned)gw < (unsigned)Wn);
                E[r * 39 + col] = unpackbf(ok ? u : p0);
            }
            if (col < 6) {
                int gw = w0 + 29 + col;
                int gwc = min(max(gw, 0), Wn - 1);
                unsigned u = plane[ghc * Wn + gwc];
                bool ok = rok && ((unsigned)gw < (unsigned)Wn);
                E[r * 39 + col + 32] = unpackbf(ok ? u : p0);
            }
        }
    }
}

__global__ __launch_bounds__(256) void k_morph_stats(
    const unsigned* __restrict__ ef, const float* __restrict__ wg,
    float* __restrict__ part) {
    __shared__ float2 E[38 * 39];
    __shared__ float redS[4][6], redQ[4][6];
    const int tid = threadIdx.x;
    const int p = blockIdx.y;            // b*64 + c
    const int c = p & 63;
    const int t = blockIdx.x;            // 36 tiles
    const int h0 = (t / 6) * 32, w0 = (t % 6) * 32;
    const unsigned p0 = packbf(__expf(-MSHIFT), __expf(-MSHIFT));

    stage_t<38>(E, ef + (size_t)p * HWn, h0, w0, tid, p0);
    __syncthreads();

    const int px3 = (tid & 31) + 3;
    const int r0 = (tid >> 5) * 4;
    float s[6] = {0,0,0,0,0,0}, q[6] = {0,0,0,0,0,0};
#pragma unroll
    for (int br = 0; br < 3; ++br) {
        const int d = br + 1, nr = 4 + 2 * d;
        float SEa[4] = {0,0,0,0}, SDa[4] = {0,0,0,0};
#pragma unroll
        for (int j = 0; j < 3; ++j) {
            float WE3[3], WD3[3];
#pragma unroll
            for (int i = 0; i < 3; ++i) {
                WE3[i] = wg[(br * 64 + c) * 9 + i * 3 + j];
                WD3[i] = wg[((br + 3) * 64 + c) * 9 + i * 3 + j];
            }
            float2 cv[10];
#pragma unroll
            for (int r = 0; r < nr; ++r)
                cv[r] = E[(r0 + 3 - d + r) * 39 + px3 + (j - 1) * d];
#pragma unroll
            for (int k = 0; k < 4; ++k)
#pragma unroll
                for (int i = 0; i < 3; ++i) {
                    SEa[k] = fmaf(WE3[i], cv[k + i * d].x, SEa[k]);
                    SDa[k] = fmaf(WD3[i], cv[k + i * d].y, SDa[k]);
                }
        }
#pragma unroll
        for (int k = 0; k < 4; ++k) {
            float me = -(__logf(fmaxf(SEa[k], SFLOOR)) + MSHIFT) * INV_BETA;
            float md =  (__logf(fmaxf(SDa[k], SFLOOR)) + MSHIFT) * INV_BETA;
            s[br]     += me; q[br]     = fmaf(me, me, q[br]);
            s[br + 3] += md; q[br + 3] = fmaf(md, md, q[br + 3]);
        }
    }
    const int lane = tid & 63, wv = tid >> 6;
#pragma unroll
    for (int v = 0; v < 6; ++v) {
        float a = s[v], b2 = q[v];
#pragma unroll
        for (int off = 32; off; off >>= 1) {
            a  += __shfl_down(a, off, 64);
            b2 += __shfl_down(b2, off, 64);
        }
        if (lane == 0) { redS[wv][v] = a; redQ[wv][v] = b2; }
    }
    __syncthreads();
    const int bt = (p >> 6) * 36 + t;
    if (tid < 6)
        part[(tid * 64 + c) * 288 + bt] =
            redS[0][tid] + redS[1][tid] + redS[2][tid] + redS[3][tid];
    else if (tid < 12) {
        int v = tid - 6;
        part[(384 + v * 64 + c) * 288 + bt] =
            redQ[0][v] + redQ[1][v] + redQ[2][v] + redQ[3][v];
    }
}

__global__ __launch_bounds__(256) void k_red(const float* __restrict__ part,
                                             float* __restrict__ sums) {
    const int w = blockIdx.x * 4 + (threadIdx.x >> 6);   // 0..767
    const int lane = threadIdx.x & 63;
    const float* src = part + (size_t)w * 288;
    float a = 0.f;
    for (int i = lane; i < 288; i += 64) a += src[i];
#pragma unroll
    for (int off = 32; off; off >>= 1) a += __shfl_down(a, off, 64);
    if (lane == 0) sums[w] = a;
}

__global__ void k_alpha(const float* __restrict__ sum, const float* __restrict__ sqs,
                        const float* __restrict__ bn_ge,
                        const float* __restrict__ bn_gd,
                        const float* __restrict__ conve,
                        const float* __restrict__ convd,
                        float* __restrict__ alpha) {
    int tid = threadIdx.x;
    if (tid >= 384) return;
    float mean = sum[tid] * (1.0f / N1);
    float var  = sqs[tid] * (1.0f / N1) - mean * mean;
    float inv  = rsqrtf(fmaxf(var, 0.f) + EPSB);
    float g, cw, sgn;
    if (tid < 192) { g = bn_ge[tid];       cw = conve[tid];       sgn = -1.f; }
    else           { g = bn_gd[tid - 192]; cw = convd[tid - 192]; sgn =  1.f; }
    alpha[tid] = sgn * cw * g * inv * INV_BETA;
}

__global__ __launch_bounds__(256) void k_reduce_c(
    const unsigned* __restrict__ ef, const float* __restrict__ wg,
    const float* __restrict__ alpha,
    float* __restrict__ pye, float* __restrict__ pyd) {
    __shared__ float2 EB[2][22 * 39];
    const int tid = threadIdx.x;
    const int t = blockIdx.x;             // 72 tiles (16x32)
    const int bz = blockIdx.y;            // b*2 + q
    const int b = bz >> 1, qh = bz & 1;
    const int h0 = (t / 6) * 16, w0 = (t % 6) * 32;
    const int c0 = qh * 32;
    const int px3 = (tid & 31) + 3;
    const int r0 = (tid >> 5) * 2;
    const unsigned p0 = packbf(__expf(-MSHIFT), __expf(-MSHIFT));
    float accE[2] = {0,0}, accD[2] = {0,0};

    const unsigned* base = ef + (size_t)(b * 64 + c0) * HWn;
    stage_t<22>(EB[0], base, h0, w0, tid, p0);
    __syncthreads();

    for (int ci = 0; ci < 32; ++ci) {
        const int c = c0 + ci;
        const float2* E = EB[ci & 1];
        if (ci < 31)
            stage_t<22>(EB[(ci + 1) & 1], base + (size_t)(ci + 1) * HWn, h0, w0, tid, p0);
#pragma unroll
        for (int br = 0; br < 3; ++br) {
            const int d = br + 1, nr = 2 + 2 * d;
            const float aE = alpha[br * 64 + c];
            const float aD = alpha[(br + 3) * 64 + c];
            float SEa[2] = {0,0}, SDa[2] = {0,0};
#pragma unroll
            for (int j = 0; j < 3; ++j) {
                float WE3[3], WD3[3];
#pragma unroll
                for (int i = 0; i < 3; ++i) {
                    WE3[i] = wg[(br * 64 + c) * 9 + i * 3 + j];
                    WD3[i] = wg[((br + 3) * 64 + c) * 9 + i * 3 + j];
                }
                float2 cv[8];
#pragma unroll
                for (int r = 0; r < nr; ++r)
                    cv[r] = E[(r0 + 3 - d + r) * 39 + px3 + (j - 1) * d];
#pragma unroll
                for (int k = 0; k < 2; ++k)
#pragma unroll
                    for (int i = 0; i < 3; ++i) {
                        SEa[k] = fmaf(WE3[i], cv[k + i * d].x, SEa[k]);
                        SDa[k] = fmaf(WD3[i], cv[k + i * d].y, SDa[k]);
                    }
            }
#pragma unroll
            for (int k = 0; k < 2; ++k) {
                accE[k] = fmaf(aE, __logf(fmaxf(SEa[k], SFLOOR)), accE[k]);
                accD[k] = fmaf(aD, __logf(fmaxf(SDa[k], SFLOOR)), accD[k]);
            }
        }
        __syncthreads();
    }
#pragma unroll
    for (int k = 0; k < 2; ++k) {
        int idx = qh * N1 + b * HWn + (h0 + r0 + k) * Wn + (w0 + px3 - 3);
        pye[idx] = accE[k];
        pyd[idx] = accD[k];
    }
}

__global__ __launch_bounds__(256) void k_merge(
    const float* __restrict__ pye, const float* __restrict__ pyd,
    float* __restrict__ ye, float* __restrict__ yd, float* __restrict__ scal) {
    int i = blockIdx.x * 256 + threadIdx.x;
    float a  = pye[i] + pye[N1 + i];
    float bb = pyd[i] + pyd[N1 + i];
    ye[i] = a; yd[i] = bb;
    float v[4] = {a, a * a, bb, bb * bb};
    __shared__ float red[4][4];
    int lane = threadIdx.x & 63, wv = threadIdx.x >> 6;
#pragma unroll
    for (int k = 0; k < 4; ++k) {
        float tv = v[k];
#pragma unroll
        for (int off = 32; off; off >>= 1) tv += __shfl_down(tv, off, 64);
        if (lane == 0) red[wv][k] = tv;
    }
    __syncthreads();
    if (threadIdx.x < 4)
        atomicAdd(&scal[threadIdx.x],
                  red[0][threadIdx.x] + red[1][threadIdx.x] + red[2][threadIdx.x] + red[3][threadIdx.x]);
}

__global__ __launch_bounds__(256) void k_final(
    const float* __restrict__ ye, const float* __restrict__ yd,
    const float* __restrict__ scal,
    const float* __restrict__ g_e, const float* __restrict__ b_e,
    const float* __restrict__ g_d, const float* __restrict__ b_d,
    float* __restrict__ out) {
    int i = blockIdx.x * 256 + threadIdx.x;
    float me_ = scal[0] * (1.0f / N1);
    float ve  = scal[1] * (1.0f / N1) - me_ * me_;
    float ie  = rsqrtf(fmaxf(ve, 0.f) + EPSB);
    float md_ = scal[2] * (1.0f / N1);
    float vd  = scal[3] * (1.0f / N1) - md_ * md_;
    float idv = rsqrtf(fmaxf(vd, 0.f) + EPSB);
    float ge = g_e[0], be = b_e[0];
    float gd = g_d[0], bd = b_d[0];
    int b = i / HWn, rem = i - b * HWn;
    float oe = fmaxf(ge * (ye[i] - me_) * ie + be, 0.f);
    float od = fmaxf(gd * (yd[i] - md_) * idv + bd, 0.f);
    out[(size_t)(b * 2) * HWn + rem]     = oe;
    out[(size_t)(b * 2 + 1) * HWn + rem] = od;
}

extern "C" void kernel_launch(void* const* d_in, const int* in_sizes, int n_in,
                              void* d_out, int out_size, void* d_ws, size_t ws_size,
                              hipStream_t stream) {
    const float* x     = (const float*)d_in[0];
    const float* we    = (const float*)d_in[1];
    const float* wd    = (const float*)d_in[2];
    const float* bn_ge = (const float*)d_in[3];
    const float* bn_gd = (const float*)d_in[5];
    const float* conve = (const float*)d_in[7];
    const float* convd = (const float*)d_in[8];
    const float* g_e   = (const float*)d_in[9];
    const float* b_e   = (const float*)d_in[10];
    const float* g_d   = (const float*)d_in[11];
    const float* b_d   = (const float*)d_in[12];
    float* ws = (float*)d_ws;
    unsigned* ef = (unsigned*)d_ws + WS_EF;

    hipMemsetAsync(ws + WS_SCAL, 0, 4 * sizeof(float), stream);
    hipLaunchKernelGGL(k_wexp, dim3(14), dim3(256), 0, stream, we, wd, ws + WS_WG);
    hipLaunchKernelGGL(k_exp, dim3(512 * HWn / 256), dim3(256), 0, stream, x, ef);
    hipLaunchKernelGGL(k_morph_stats, dim3(36, 512), dim3(256), 0, stream,
                       ef, ws + WS_WG, ws + WS_PART);
    hipLaunchKernelGGL(k_red, dim3(192), dim3(256), 0, stream, ws + WS_PART, ws + WS_SUM);
    hipLaunchKernelGGL(k_alpha, dim3(1), dim3(384), 0, stream,
                       ws + WS_SUM, ws + WS_SQS, bn_ge, bn_gd, conve, convd, ws + WS_ALPHA);
    hipLaunchKernelGGL(k_reduce_c, dim3(72, 16), dim3(256), 0, stream,
                       ef, ws + WS_WG, ws + WS_ALPHA, ws + WS_PYE, ws + WS_PYD);
    hipLaunchKernelGGL(k_merge, dim3(1152), dim3(256), 0, stream,
                       ws + WS_PYE, ws + WS_PYD, ws + WS_YE, ws + WS_YD, ws + WS_SCAL);
    hipLaunchKernelGGL(k_final, dim3(1152), dim3(256), 0, stream,
                       ws + WS_YE, ws + WS_YD, ws + WS_SCAL, g_e, b_e, g_d, b_d,
                       (float*)d_out);
}